// Round 5
// baseline (781.001 us; speedup 1.0000x reference)
//
#include <hip/hip_runtime.h>
#include <hip/hip_bf16.h>

#define TPB 256
#define NCODES 1024
#define DIMS 256
#define PIXB 64
#define XPAD 264      // xs row stride in ushorts (528 B): bfr reads land on b128 floor, no extra conflicts
#define DELTA 3.0f    // screening margin; bf16 dot error worst-case ~1.3, margin 2.6 needed
#define CAP 8         // candidates per pixel; overflow -> exact full rescan

typedef __attribute__((ext_vector_type(8))) short bf16x8;
typedef __attribute__((ext_vector_type(4))) float f32x4;

// order-preserving float->uint map for atomicMin
__device__ __forceinline__ unsigned fkey(float f) {
    unsigned u = __float_as_uint(f);
    return (u & 0x80000000u) ? ~u : (u | 0x80000000u);
}
__device__ __forceinline__ float funkey(unsigned k) {
    return (k & 0x80000000u) ? __uint_as_float(k & 0x7fffffffu) : __uint_as_float(~k);
}

// prep: ebc = bf16(emb) in chunk-major layout [kc][code][32 dims] (64 B rows),
// so vq staging reads are wave-contiguous 1 KB. e2 = exact fp32 row norms.
__global__ __launch_bounds__(64) void prep_kernel(const float* __restrict__ emb,
                                                  ushort* __restrict__ ebc,
                                                  float* __restrict__ e2) {
    const int c = blockIdx.x;
    const int l = threadIdx.x;           // lane l holds dims 4l..4l+3 (kc = l>>3)
    float4 v = *(const float4*)(emb + (size_t)c * DIMS + 4 * l);
    __hip_bfloat16 h0 = __float2bfloat16(v.x), h1 = __float2bfloat16(v.y);
    __hip_bfloat16 h2 = __float2bfloat16(v.z), h3 = __float2bfloat16(v.w);
    ushort4 u;
    u.x = *(ushort*)&h0; u.y = *(ushort*)&h1; u.z = *(ushort*)&h2; u.w = *(ushort*)&h3;
    *(ushort4*)(ebc + (size_t)(l >> 3) * 32768 + c * 32 + (l & 7) * 4) = u;
    float s = v.x * v.x + v.y * v.y + v.z * v.z + v.w * v.w;
#pragma unroll
    for (int off = 1; off < 64; off <<= 1) s += __shfl_xor(s, off);
    if (l == 0) e2[c] = s;
}

__global__ __launch_bounds__(TPB, 3) void vq_kernel(const float* __restrict__ z,
                                                    const float* __restrict__ emb,
                                                    const ushort* __restrict__ ebc,
                                                    const float* __restrict__ e2g,
                                                    int* __restrict__ out) {
    // 33792 + 16384 + 1024 + 256 + 256 + 2048 = 53760 B -> 3 blocks/CU (160 KiB LDS)
    __shared__ __align__(16) ushort xs[PIXB * XPAD];   // bf16 x, [px][dim]
    __shared__ __align__(16) ushort es[256 * 32];      // bf16 e tile [code][32], unit-swizzled
    __shared__ float    e2s[256];                      // per-cc chunk of e2
    __shared__ unsigned minkey[PIXB];
    __shared__ int      cnt[PIXB];
    __shared__ int      cand[PIXB * CAP];

    const int tid = threadIdx.x;
    const int w   = tid >> 6;     // wave 0..3
    const int L   = tid & 63;
    const int col = L & 15;       // MFMA col (pixel within n-tile / code within m-tile)
    const int q   = L >> 4;       // MFMA quad
    const int pixbase = blockIdx.x * PIXB;
    const int t  = pixbase >> 12;
    const int n0 = pixbase & 4095;

    // ---- phase 1: coalesced z load (float4 over px), bf16 transpose into LDS ----
    {
        const int pq = L & 15;    // which float4 of the 64-px row
        const int dq = L >> 4;    // dim within group of 4
#pragma unroll
        for (int i = 0; i < 16; ++i) {
            const int d = w * 64 + i * 4 + dq;
            const float4 v = *(const float4*)(z + (((size_t)(t * DIMS + d)) << 12) + n0 + 4 * pq);
            __hip_bfloat16 h0 = __float2bfloat16(v.x), h1 = __float2bfloat16(v.y);
            __hip_bfloat16 h2 = __float2bfloat16(v.z), h3 = __float2bfloat16(v.w);
            xs[(4 * pq + 0) * XPAD + d] = *(ushort*)&h0;
            xs[(4 * pq + 1) * XPAD + d] = *(ushort*)&h1;
            xs[(4 * pq + 2) * XPAD + d] = *(ushort*)&h2;
            xs[(4 * pq + 3) * XPAD + d] = *(ushort*)&h3;
        }
    }
    if (tid < 64) { minkey[tid] = 0xFFFFFFFFu; cnt[tid] = 0; }

    // staging-store constants: thread stores 4 units; row j*64 + (tid>>2), unit tid&3
    const int srow = tid >> 2;
    const int sphys = (tid & 3) ^ ((tid >> 3) & 3);    // XOR unit swizzle, ((row)>>1)&3 = (tid>>3)&3
    const int sw2 = (col >> 1) & 3;                    // read-side swizzle key
    const uint4* __restrict__ esrc = (const uint4*)ebc;

    // ---- phase 2: MFMA with register-prefetched LDS staging ----
#pragma unroll 1
    for (int cc = 0; cc < 4; ++cc) {
        uint4 r[4], rn[4];
        {   // preload kc=0 chunk (global, coalesced 1 KB per instr)
            const size_t b = (size_t)cc * 1024 + tid;
#pragma unroll
            for (int j = 0; j < 4; ++j) r[j] = esrc[b + j * 256];
        }
        __syncthreads();                       // prev cc done with es/e2s/minkey reads
        e2s[tid] = e2g[cc * 256 + tid];

        f32x4 acc[4][4];
#pragma unroll
        for (int mt = 0; mt < 4; ++mt)
#pragma unroll
            for (int nt = 0; nt < 4; ++nt) acc[mt][nt] = (f32x4){0.f, 0.f, 0.f, 0.f};

#pragma unroll 1
        for (int kc = 0; kc < 8; ++kc) {
            if (kc) __syncthreads();           // prev MFMA consumers done before overwrite
#pragma unroll
            for (int j = 0; j < 4; ++j)
                *(uint4*)&es[(j * 64 + srow) * 32 + sphys * 8] = r[j];
            if (kc < 7) {                      // prefetch next chunk; flies during MFMAs
                const size_t b = (size_t)(kc + 1) * 4096 + cc * 1024 + tid;
#pragma unroll
                for (int j = 0; j < 4; ++j) rn[j] = esrc[b + j * 256];
            }
            __syncthreads();                   // es tile ready

            bf16x8 af[4], bfr[4];
#pragma unroll
            for (int mt = 0; mt < 4; ++mt) {
                const int row = w * 64 + mt * 16 + col;
                af[mt] = *(const bf16x8*)&es[row * 32 + ((q ^ sw2) * 8)];
            }
#pragma unroll
            for (int nt = 0; nt < 4; ++nt)
                bfr[nt] = *(const bf16x8*)&xs[(nt * 16 + col) * XPAD + kc * 32 + q * 8];
#pragma unroll
            for (int mt = 0; mt < 4; ++mt)
#pragma unroll
                for (int nt = 0; nt < 4; ++nt)
                    acc[mt][nt] = __builtin_amdgcn_mfma_f32_16x16x32_bf16(
                        af[mt], bfr[nt], acc[mt][nt], 0, 0, 0);
#pragma unroll
            for (int j = 0; j < 4; ++j) r[j] = rn[j];
        }

        // epilogue: s = e2[c] - 2*dot ; C layout col=px, row=q*4+r_
        f32x4 e2r[4];
#pragma unroll
        for (int mt = 0; mt < 4; ++mt)
            e2r[mt] = *(const f32x4*)&e2s[w * 64 + mt * 16 + q * 4];
#pragma unroll
        for (int nt = 0; nt < 4; ++nt) {
            float m = 3.4e38f;
#pragma unroll
            for (int mt = 0; mt < 4; ++mt)
#pragma unroll
                for (int r_ = 0; r_ < 4; ++r_)
                    m = fminf(m, e2r[mt][r_] - 2.f * acc[mt][nt][r_]);
            m = fminf(m, __shfl_xor(m, 16));
            m = fminf(m, __shfl_xor(m, 32));
            if (q == 0) atomicMin(&minkey[nt * 16 + col], fkey(m));
        }
        __syncthreads();                       // all minkey updates visible
#pragma unroll
        for (int nt = 0; nt < 4; ++nt) {
            const int px = nt * 16 + col;
            const float thr = funkey(minkey[px]) + DELTA;   // running-min superset bound
#pragma unroll
            for (int mt = 0; mt < 4; ++mt)
#pragma unroll
                for (int r_ = 0; r_ < 4; ++r_) {
                    float s = e2r[mt][r_] - 2.f * acc[mt][nt][r_];
                    if (s <= thr) {
                        int pos = atomicAdd(&cnt[px], 1);
                        if (pos < CAP)
                            cand[px * CAP + pos] = cc * 256 + w * 64 + mt * 16 + q * 4 + r_;
                    }
                }
        }
    }
    __syncthreads();

    // ---- phase 3: exact fp32 rescore; wave w handles px w*16..+15 (e2 from global!) ----
#pragma unroll 1
    for (int pi = 0; pi < 16; ++pi) {
        const int px = w * 16 + pi;
        const int n  = cnt[px];
        const float* zp = z + (((size_t)t * DIMS + 4 * L) << 12) + n0 + px;
        float x0 = zp[0];
        float x1 = zp[(size_t)1 << 12];
        float x2 = zp[(size_t)2 << 12];
        float x3 = zp[(size_t)3 << 12];
        float bs = 3.4e38f;
        int   bi = 0;
        if (n <= CAP) {
            for (int k = 0; k < n; ++k) {
                int c = cand[px * CAP + k];
                float4 ev = *(const float4*)(emb + (size_t)c * DIMS + 4 * L);
                float p = x0 * ev.x + x1 * ev.y + x2 * ev.z + x3 * ev.w;
#pragma unroll
                for (int off = 1; off < 64; off <<= 1) p += __shfl_xor(p, off);
                float s = e2g[c] - 2.f * p;
                if (s < bs || (s == bs && c < bi)) { bs = s; bi = c; }
            }
        } else {
            // overflow fallback (rare): exact scan of all codes
            for (int c = 0; c < NCODES; ++c) {
                float4 ev = *(const float4*)(emb + (size_t)c * DIMS + 4 * L);
                float p = x0 * ev.x + x1 * ev.y + x2 * ev.z + x3 * ev.w;
#pragma unroll
                for (int off = 1; off < 64; off <<= 1) p += __shfl_xor(p, off);
                float s = e2g[c] - 2.f * p;
                if (s < bs || (s == bs && c < bi)) { bs = s; bi = c; }
            }
        }
        if (L == 0) out[pixbase + px] = bi;
    }
}

extern "C" void kernel_launch(void* const* d_in, const int* in_sizes, int n_in,
                              void* d_out, int out_size, void* d_ws, size_t ws_size,
                              hipStream_t stream) {
    const float* z   = (const float*)d_in[0];   // (16,256,64,64) fp32
    const float* emb = (const float*)d_in[1];   // (1024,256) fp32
    int* out = (int*)d_out;                     // (16,64,64) int32

    ushort* ebc = (ushort*)d_ws;                                         // 512 KB chunk-major bf16
    float*  e2  = (float*)((char*)d_ws + (size_t)NCODES * DIMS * sizeof(ushort)); // 4 KB

    prep_kernel<<<NCODES, 64, 0, stream>>>(emb, ebc, e2);
    vq_kernel<<<(16 * 64 * 64) / PIXB, TPB, 0, stream>>>(z, emb, ebc, e2, out);
}

// Round 6
// 562.215 us; speedup vs baseline: 1.3892x; 1.3892x over previous
//
#include <hip/hip_runtime.h>
#include <hip/hip_bf16.h>

#define TPB 256
#define NCODES 1024
#define DIMS 256
#define PIXB 64
#define XPAD 264      // xs row stride (ushorts): (col + kc*4 + q) mod 8 spread -> 2-way reads (free)
#define XS3 68        // phase-3 fp32 x-stage row stride (floats): px*17 mod 8 spread -> free
#define DELTA 3.0f    // screening margin; bf16 dot error worst-case ~2.6 in distance units
#define CAP 8         // candidates per pixel; overflow -> exact full rescan

typedef __attribute__((ext_vector_type(8))) short bf16x8;
typedef __attribute__((ext_vector_type(4))) float f32x4;

// order-preserving float->uint map for atomicMin
__device__ __forceinline__ unsigned fkey(float f) {
    unsigned u = __float_as_uint(f);
    return (u & 0x80000000u) ? ~u : (u | 0x80000000u);
}
__device__ __forceinline__ float funkey(unsigned k) {
    return (k & 0x80000000u) ? __uint_as_float(k & 0x7fffffffu) : __uint_as_float(~k);
}

// async global->LDS DMA, 16 B per lane; LDS dest = wave-uniform base + lane*16
__device__ __forceinline__ void gl_lds16(const void* g, void* l) {
    __builtin_amdgcn_global_load_lds(
        (const __attribute__((address_space(1))) unsigned int*)g,
        (__attribute__((address_space(3))) unsigned int*)l, 16, 0, 0);
}

// prep: ebc = bf16(emb), chunk-major [cc][kc][256 rows x 32 dims], with the 16B units
// of each row XOR-swizzled (u ^= (row>>1)&3) so the vq DMA lands them bank-conflict-free.
// e2 = exact fp32 row norms.
__global__ __launch_bounds__(64) void prep_kernel(const float* __restrict__ emb,
                                                  ushort* __restrict__ ebc,
                                                  float* __restrict__ e2) {
    const int c = blockIdx.x;
    const int l = threadIdx.x;           // lane l holds dims 4l..4l+3
    float4 v = *(const float4*)(emb + (size_t)c * DIMS + 4 * l);
    __hip_bfloat16 h0 = __float2bfloat16(v.x), h1 = __float2bfloat16(v.y);
    __hip_bfloat16 h2 = __float2bfloat16(v.z), h3 = __float2bfloat16(v.w);
    ushort4 u4;
    u4.x = *(ushort*)&h0; u4.y = *(ushort*)&h1; u4.z = *(ushort*)&h2; u4.w = *(ushort*)&h3;
    const int kc   = l >> 3;             // 32-dim chunk
    const int u    = (l & 7) >> 1;       // 16B unit within chunk (q)
    const int half = l & 1;              // 8B half within unit
    const int cc   = c >> 8;
    const int row  = c & 255;
    const int unit = row * 4 + (u ^ ((row >> 1) & 3));
    *(ushort4*)(ebc + (size_t)(cc * 8 + kc) * 8192 + unit * 8 + half * 4) = u4;
    float s = v.x * v.x + v.y * v.y + v.z * v.z + v.w * v.w;
#pragma unroll
    for (int off = 1; off < 64; off <<= 1) s += __shfl_xor(s, off);
    if (l == 0) e2[c] = s;
}

__global__ __launch_bounds__(TPB, 2) void vq_kernel(const float* __restrict__ z,
                                                    const float* __restrict__ emb,
                                                    const ushort* __restrict__ ebc,
                                                    const float* __restrict__ e2g,
                                                    int* __restrict__ out) {
    // 33792 + 16384 + 1024 + 256 + 256 + 2048 = 53760 B -> 3 blocks/CU
    __shared__ __align__(16) ushort xs[PIXB * XPAD];   // bf16 x, [px][dim]; phase-3 reuses as fp32 stage
    __shared__ __align__(16) ushort es[256 * 32];      // bf16 e tile, swizzled physical layout
    __shared__ float    e2s[256];
    __shared__ unsigned minkey[PIXB];
    __shared__ int      cnt[PIXB];
    __shared__ int      cand[PIXB * CAP];

    const int tid = threadIdx.x;
    const int w   = tid >> 6;     // wave 0..3
    const int L   = tid & 63;
    const int col = L & 15;       // MFMA col (pixel in B / code in A)
    const int q   = L >> 4;       // MFMA quad
    const int pixbase = blockIdx.x * PIXB;
    const int t  = pixbase >> 12;
    const int n0 = pixbase & 4095;

    // ---- phase 1: coalesced z float4 loads, bf16 transpose into LDS ----
    {
        const int pq = L & 15;    // which px-quad
        const int dq = L >> 4;    // dim within group of 4
#pragma unroll
        for (int i = 0; i < 16; ++i) {
            const int d = w * 64 + i * 4 + dq;
            const float4 v = *(const float4*)(z + (((size_t)(t * DIMS + d)) << 12) + n0 + 4 * pq);
            __hip_bfloat16 h0 = __float2bfloat16(v.x), h1 = __float2bfloat16(v.y);
            __hip_bfloat16 h2 = __float2bfloat16(v.z), h3 = __float2bfloat16(v.w);
            xs[(4 * pq + 0) * XPAD + d] = *(ushort*)&h0;
            xs[(4 * pq + 1) * XPAD + d] = *(ushort*)&h1;
            xs[(4 * pq + 2) * XPAD + d] = *(ushort*)&h2;
            xs[(4 * pq + 3) * XPAD + d] = *(ushort*)&h3;
        }
    }
    if (tid < 64) { minkey[tid] = 0xFFFFFFFFu; cnt[tid] = 0; }

    const int swz = (col >> 1) & 3;      // af read-side swizzle key

    // ---- phase 2: MFMA screening, es staged via global_load_lds DMA ----
#pragma unroll 1
    for (int cc = 0; cc < 4; ++cc) {
        __syncthreads();                  // prev cc fully consumed (es, e2s, minkey)
        e2s[tid] = e2g[cc * 256 + tid];

        f32x4 acc[4][4];
#pragma unroll
        for (int mt = 0; mt < 4; ++mt)
#pragma unroll
            for (int nt = 0; nt < 4; ++nt) acc[mt][nt] = (f32x4){0.f, 0.f, 0.f, 0.f};

#pragma unroll 1
        for (int kc = 0; kc < 8; ++kc) {
            if (kc) __syncthreads();      // prev af reads done before overwrite
            {   // wave w DMAs its 4KB quarter: 4 issues x (64 lanes x 16B)
                const ushort* gb = ebc + (size_t)(cc * 8 + kc) * 8192 + w * 2048 + L * 8;
                ushort* lb = es + w * 2048;
#pragma unroll
                for (int j = 0; j < 4; ++j)
                    gl_lds16(gb + j * 512, lb + j * 512);
            }
            __syncthreads();              // barrier drains vmcnt -> DMA complete

            bf16x8 af[4], bfr[4];
#pragma unroll
            for (int mt = 0; mt < 4; ++mt) {
                const int row = w * 64 + mt * 16 + col;
                af[mt] = *(const bf16x8*)&es[row * 32 + ((q ^ swz) << 3)];
            }
#pragma unroll
            for (int nt = 0; nt < 4; ++nt)
                bfr[nt] = *(const bf16x8*)&xs[(nt * 16 + col) * XPAD + kc * 32 + q * 8];
#pragma unroll
            for (int mt = 0; mt < 4; ++mt)
#pragma unroll
                for (int nt = 0; nt < 4; ++nt)
                    acc[mt][nt] = __builtin_amdgcn_mfma_f32_16x16x32_bf16(
                        af[mt], bfr[nt], acc[mt][nt], 0, 0, 0);
        }

        // epilogue: s = e2[c] - 2*dot ; C layout col=px, row=q*4+r_
        f32x4 e2r[4];
#pragma unroll
        for (int mt = 0; mt < 4; ++mt)
            e2r[mt] = *(const f32x4*)&e2s[w * 64 + mt * 16 + q * 4];
#pragma unroll
        for (int nt = 0; nt < 4; ++nt) {
            float m = 3.4e38f;
#pragma unroll
            for (int mt = 0; mt < 4; ++mt)
#pragma unroll
                for (int r_ = 0; r_ < 4; ++r_)
                    m = fminf(m, e2r[mt][r_] - 2.f * acc[mt][nt][r_]);
            m = fminf(m, __shfl_xor(m, 16));
            m = fminf(m, __shfl_xor(m, 32));
            if (q == 0) atomicMin(&minkey[nt * 16 + col], fkey(m));
        }
        __syncthreads();                  // minkey updates visible
#pragma unroll
        for (int nt = 0; nt < 4; ++nt) {
            const int px = nt * 16 + col;
            const float thr = funkey(minkey[px]) + DELTA;   // running min -> superset guarantee
#pragma unroll
            for (int mt = 0; mt < 4; ++mt)
#pragma unroll
                for (int r_ = 0; r_ < 4; ++r_) {
                    float s = e2r[mt][r_] - 2.f * acc[mt][nt][r_];
                    if (s <= thr) {
                        int pos = atomicAdd(&cnt[px], 1);
                        if (pos < CAP)
                            cand[px * CAP + pos] = cc * 256 + w * 64 + mt * 16 + q * 4 + r_;
                    }
                }
        }
    }
    __syncthreads();                      // all candidate lists final

    // ---- phase 3: exact fp32 rescore from LDS-staged z chunks ----
    float* xstage = (float*)xs;           // 64 x XS3 fp32 = 17408 B, xs region is dead now
    const int px  = w * 16 + (L & 15);
    const int n   = cnt[px];
    const bool ovf = (n > CAP);
    const int ns  = ovf ? 0 : n;
    const int s0  = L >> 4;               // this lane's candidate slots: s0 and s0+4
    const int c0  = (s0 < ns)     ? cand[px * CAP + s0]     : -1;
    const int c1  = (s0 + 4 < ns) ? cand[px * CAP + s0 + 4] : -1;
    float a0 = 0.f, a1 = 0.f;

#pragma unroll 1
    for (int dc = 0; dc < 4; ++dc) {
        if (dc) __syncthreads();          // prev chunk's readers done
        {   // stage 64 dims x 64 px fp32: lane L = px, wave w = dims w*16..+15 (coalesced 256B)
            const float* zp = z + (((size_t)(t * DIMS + dc * 64 + w * 16)) << 12) + n0 + L;
            float* xrow = xstage + L * XS3 + w * 16;
#pragma unroll
            for (int j = 0; j < 16; ++j)
                xrow[j] = zp[(size_t)j << 12];
        }
        __syncthreads();
        const float* xv = xstage + px * XS3;
        if (c0 >= 0) {
            const float4* ep = (const float4*)(emb + (size_t)c0 * DIMS + dc * 64);
#pragma unroll
            for (int d4 = 0; d4 < 16; ++d4) {
                float4 x4 = *(const float4*)(xv + 4 * d4);
                float4 e4 = ep[d4];
                a0 += x4.x * e4.x + x4.y * e4.y + x4.z * e4.z + x4.w * e4.w;
            }
        }
        if (c1 >= 0) {
            const float4* ep = (const float4*)(emb + (size_t)c1 * DIMS + dc * 64);
#pragma unroll
            for (int d4 = 0; d4 < 16; ++d4) {
                float4 x4 = *(const float4*)(xv + 4 * d4);
                float4 e4 = ep[d4];
                a1 += x4.x * e4.x + x4.y * e4.y + x4.z * e4.z + x4.w * e4.w;
            }
        }
    }
    {   // per-lane best of 2 slots, then combine the 4 lanes sharing this px
        float bd = 3.4e38f; int bi_ = 0x7fffffff;
        if (c0 >= 0) { float s = e2g[c0] - 2.f * a0; if (s < bd || (s == bd && c0 < bi_)) { bd = s; bi_ = c0; } }
        if (c1 >= 0) { float s = e2g[c1] - 2.f * a1; if (s < bd || (s == bd && c1 < bi_)) { bd = s; bi_ = c1; } }
#pragma unroll
        for (int off = 16; off < 64; off <<= 1) {
            float d2 = __shfl_xor(bd, off);
            int   i2 = __shfl_xor(bi_, off);
            if (d2 < bd || (d2 == bd && i2 < bi_)) { bd = d2; bi_ = i2; }
        }
        if (L < 16 && !ovf) out[pixbase + px] = bi_;
    }

    // overflow fallback (rare): exact full scan for px's with cnt > CAP
#pragma unroll 1
    for (int pi = 0; pi < 16; ++pi) {
        const int fpx = w * 16 + pi;
        if (cnt[fpx] <= CAP) continue;    // wave-uniform branch
        const float* zp = z + (((size_t)t * DIMS + 4 * L) << 12) + n0 + fpx;
        float x0 = zp[0];
        float x1 = zp[(size_t)1 << 12];
        float x2 = zp[(size_t)2 << 12];
        float x3 = zp[(size_t)3 << 12];
        float bs = 3.4e38f;
        int   bi = 0;
        for (int c = 0; c < NCODES; ++c) {
            float4 ev = *(const float4*)(emb + (size_t)c * DIMS + 4 * L);
            float p = x0 * ev.x + x1 * ev.y + x2 * ev.z + x3 * ev.w;
#pragma unroll
            for (int off = 1; off < 64; off <<= 1) p += __shfl_xor(p, off);
            float s = e2g[c] - 2.f * p;
            if (s < bs || (s == bs && c < bi)) { bs = s; bi = c; }
        }
        if (L == 0) out[pixbase + fpx] = bi;
    }
}

extern "C" void kernel_launch(void* const* d_in, const int* in_sizes, int n_in,
                              void* d_out, int out_size, void* d_ws, size_t ws_size,
                              hipStream_t stream) {
    const float* z   = (const float*)d_in[0];   // (16,256,64,64) fp32
    const float* emb = (const float*)d_in[1];   // (1024,256) fp32
    int* out = (int*)d_out;                     // (16,64,64) int32

    ushort* ebc = (ushort*)d_ws;                                         // 512 KB swizzled bf16
    float*  e2  = (float*)((char*)d_ws + (size_t)NCODES * DIMS * sizeof(ushort)); // 4 KB

    prep_kernel<<<NCODES, 64, 0, stream>>>(emb, ebc, e2);
    vq_kernel<<<(16 * 64 * 64) / PIXB, TPB, 0, stream>>>(z, emb, ebc, e2, out);
}